// Round 9
// baseline (1513.709 us; speedup 1.0000x reference)
//
#include <hip/hip_runtime.h>
#include <hip/hip_bf16.h>
#include <cstdint>
#include <cstddef>

constexpr int SDIM = 6;
constexpr int SCOR = 64;   // 2^6 corners
typedef unsigned short u16;
typedef __attribute__((ext_vector_type(8))) short bf16x8;
typedef __attribute__((ext_vector_type(4))) float f32x4;

__device__ __forceinline__ float bf2f(u16 h) {
    union { unsigned u; float f; } v; v.u = ((unsigned)h) << 16; return v.f;
}
__device__ __forceinline__ u16 f2bf(float f) {
    union { float f; unsigned u; } v; v.f = f;
    unsigned r = v.u + 0x7fffu + ((v.u >> 16) & 1u);
    return (u16)(r >> 16);
}

template <int KS>
__device__ __forceinline__ void keybasis(const float* u, int s, int& key, float& basis) {
    int idx = 0, str = 1;
    float b = 1.0f;
    #pragma unroll
    for (int d = 0; d < SDIM; d++) {
        float v = u[d] * (KS - 1);
        float fl = floorf(v);
        float fr = v - fl;
        int bit = (s >> d) & 1;
        int pos = (int)fl + bit;
        pos = min(max(pos, 0), KS - 1);
        idx += pos * str;
        str *= KS;
        b *= bit ? fr : (1.0f - fr);
    }
    key = idx;
    basis = b;
}

// ---------------- fused zero + fp32->bf16 ----------------
__global__ __launch_bounds__(256) void prep_kernel(int* __restrict__ zb, int nz,
                                                   const float* __restrict__ xin,
                                                   u16* __restrict__ xbf, int n4) {
    int i = blockIdx.x * blockDim.x + threadIdx.x;
    if (i < nz) zb[i] = 0;
    if (i < n4) {
        float4 v = ((const float4*)xin)[i];
        ushort4 o;
        o.x = f2bf(v.x); o.y = f2bf(v.y); o.z = f2bf(v.z); o.w = f2bf(v.w);
        ((ushort4*)xbf)[i] = o;
    }
}

// ---------------- fused counting: 3 kernel sizes + degree ----------------
__global__ __launch_bounds__(256) void count_all(const float* __restrict__ ea,
                                                 const int* __restrict__ dst,
                                                 int* __restrict__ cnt3,
                                                 int* __restrict__ cnt5,
                                                 int* __restrict__ cnt7,
                                                 int* __restrict__ degi, int P) {
    int gid = blockIdx.x * blockDim.x + threadIdx.x;
    if (gid >= P) return;
    int e = gid >> 6, s = gid & 63;
    float u[SDIM];
    #pragma unroll
    for (int d = 0; d < SDIM; d++) u[d] = ea[e * SDIM + d];
    int k; float b;
    keybasis<3>(u, s, k, b); atomicAdd(&cnt3[k], 1);
    keybasis<5>(u, s, k, b); atomicAdd(&cnt5[k], 1);
    keybasis<7>(u, s, k, b); atomicAdd(&cnt7[k], 1);
    if (s == 0) atomicAdd(&degi[dst[e]], 1);
}

// ---------------- parallel segmented scan over zb = [deg|cnt3|cnt5|cnt7] ----------------
__global__ __launch_bounds__(256) void scan_partial(const int* __restrict__ zb,
                                                    int* __restrict__ bsum) {
    int b = blockIdx.x, t = threadIdx.x;
    int4 v = *(const int4*)(zb + b * 1024 + t * 4);
    __shared__ int red[256];
    red[t] = v.x + v.y + v.z + v.w;
    __syncthreads();
    for (int h = 128; h >= 1; h >>= 1) {
        if (t < h) red[t] += red[t + h];
        __syncthreads();
    }
    if (t == 0) bsum[b] = red[0];
}

__global__ __launch_bounds__(256) void scan_final(int* __restrict__ zb,
                                                  const int* __restrict__ bsum,
                                                  int* __restrict__ eoff,
                                                  int* __restrict__ offs3,
                                                  int* __restrict__ offs5,
                                                  int* __restrict__ offs7,
                                                  int Nn, int nb0) {
    int b = blockIdx.x, t = threadIdx.x;
    int s1 = nb0, s2 = nb0 + 1, s3 = nb0 + 17;
    int seg = (b >= s3) ? 3 : (b >= s2) ? 2 : (b >= s1) ? 1 : 0;
    int sb = (seg == 0) ? 0 : (seg == 1) ? s1 : (seg == 2) ? s2 : s3;
    int L = (seg == 0) ? Nn : (seg == 1) ? 729 : (seg == 2) ? 15625 : 117649;
    int* offs = (seg == 0) ? eoff : (seg == 1) ? offs3 : (seg == 2) ? offs5 : offs7;

    __shared__ int red[256];
    int cnt = b - sb;
    int acc = 0;
    for (int j = t; j < cnt; j += 256) acc += bsum[sb + j];
    red[t] = acc;
    __syncthreads();
    for (int h = 128; h >= 1; h >>= 1) {
        if (t < h) red[t] += red[t + h];
        __syncthreads();
    }
    int blockPrefix = red[0];
    __syncthreads();

    int idx = b * 1024 + t * 4;
    int4 v = *(const int4*)(zb + idx);
    int tsum = v.x + v.y + v.z + v.w;
    __shared__ int ss[256];
    ss[t] = tsum;
    __syncthreads();
    for (int off = 1; off < 256; off <<= 1) {
        int val = (t >= off) ? ss[t - off] : 0;
        __syncthreads();
        ss[t] += val;
        __syncthreads();
    }
    int p = blockPrefix + ((t == 0) ? 0 : ss[t - 1]);
    int pe[4];
    pe[0] = p;
    pe[1] = p + v.x;
    pe[2] = pe[1] + v.y;
    pe[3] = pe[2] + v.z;
    int vv[4] = {v.x, v.y, v.z, v.w};
    int li = (b - sb) * 1024 + t * 4;
    #pragma unroll
    for (int j = 0; j < 4; j++) {
        int gi = li + j;
        if (gi < L) {
            offs[gi] = pe[j];
            zb[idx + j] = pe[j];   // cursor init
            if (gi == L - 1) offs[L] = pe[j] + vv[j];
        }
    }
}

// ---------------- fused fill: one wave = one edge; lane = corner ----------------
__global__ __launch_bounds__(256) void fill_all(const float* __restrict__ ea,
                                                const int* __restrict__ dst,
                                                int* __restrict__ ecur,
                                                int* __restrict__ cur3, int4* __restrict__ pP3,
                                                int* __restrict__ cur5, int4* __restrict__ pP5,
                                                int* __restrict__ cur7, int4* __restrict__ pP7,
                                                int P) {
    int gid = blockIdx.x * blockDim.x + threadIdx.x;
    if (gid >= P) return;
    int e = gid >> 6;
    int lane = threadIdx.x & 63;   // == corner s
    float u[SDIM];
    #pragma unroll
    for (int d = 0; d < SDIM; d++) u[d] = ea[e * SDIM + d];
    int er = 0;
    if (lane == 0) er = atomicAdd(&ecur[dst[e]], 1);
    er = __shfl(er, 0);
    int er64 = er * SCOR + lane;
    int k; float b; int slot;
    keybasis<3>(u, lane, k, b);
    slot = atomicAdd(&cur3[k], 1);
    pP3[slot] = make_int4(e, __float_as_int(b), er64, 0);
    keybasis<5>(u, lane, k, b);
    slot = atomicAdd(&cur5[k], 1);
    pP5[slot] = make_int4(e, __float_as_int(b), er64, 0);
    keybasis<7>(u, lane, k, b);
    slot = atomicAdd(&cur7[k], 1);
    pP7[slot] = make_int4(e, __float_as_int(b), er64, 0);
}

// ---------------- MFMA bucketed conv: coalesced W stage -> LDS -> breg ----------------
// W[k] staged once per block (coalesced line loads, fragment-order LDS), each
// wave vector-reads its B fragments into registers once; main loop is
// barrier-free per-wave tiles (MFMA + per-wave LDS transpose + scatter store).
template <int IN, int OUT, int WAVES, int WN, int GY>
__global__ __launch_bounds__(WAVES * 64) void conv_mfma_r(
    const u16* __restrict__ xbf, const int* __restrict__ src,
    const float* __restrict__ W, const int* __restrict__ offs,
    const int4* __restrict__ pairP, u16* __restrict__ mpart) {
    constexpr int NT = WAVES * 64;
    constexpr int WM = WAVES / WN;
    constexpr int OUT16 = (OUT + 15) & ~15;
    static_assert(OUT == OUT16, "conv_mfma_r requires OUT multiple of 16");
    constexpr int NF = OUT16 / 16;
    constexpr int NFW = NF / WN;
    constexpr int KS = IN / 32;
    constexpr int TW = NFW * 16;
    constexpr int TSTR = TW + 8;
    constexpr int CHW = TW / 8;
    static_assert((TSTR * 2) % 16 == 0, "row stride must be 16B aligned");

    __shared__ u16 Wf[IN * OUT16];
    __shared__ u16 tall[WAVES][16 * TSTR];

    int k = blockIdx.x;
    int p0 = offs[k], p1 = offs[k + 1];
    if (p0 + (int)blockIdx.y * WM * 16 >= p1) return;

    int t = threadIdx.x;
    int wid = t >> 6, lane = t & 63;
    int wm = wid % WM, wn = wid / WM;
    int l15 = lane & 15, l4 = lane >> 4;
    u16* twave = tall[wid];

    // stage W[k]: coalesced fp32 reads -> bf16 fragment-order LDS
    const float* Wg = W + (size_t)k * IN * OUT;
    #pragma unroll
    for (int f0 = 0; f0 < IN * OUT; f0 += NT) {
        int f = f0 + t;
        int i = f / OUT, o = f % OUT;
        int ks = i >> 5, koct = (i >> 3) & 3, j = i & 7, nf = o >> 4, c = o & 15;
        Wf[(((ks * NF + nf) * 16 + c) << 5) + (koct << 3) + j] = f2bf(Wg[f]);
    }
    __syncthreads();

    // one-time fragment loads into registers
    bf16x8 breg[KS][NFW];
    #pragma unroll
    for (int ks = 0; ks < KS; ks++)
        #pragma unroll
        for (int nf = 0; nf < NFW; nf++)
            breg[ks][nf] = *(const bf16x8*)&Wf[(((ks * NF + wn * NFW + nf) * 16 + l15) << 5) + (l4 << 3)];

    for (int t0 = p0 + (blockIdx.y * WM + wm) * 16; t0 < p1; t0 += WM * GY * 16) {
        int np = min(16, p1 - t0);
        int pi = t0 + l15;
        int4 meta = pairP[pi < p1 ? pi : p0];
        float basv = (l15 < np) ? __int_as_float(meta.y) : 0.0f;
        int nodev = src[meta.x];
        int srv = meta.z;

        const u16* xrow = xbf + (size_t)nodev * IN + l4 * 8;

        f32x4 acc[NFW];
        #pragma unroll
        for (int nf = 0; nf < NFW; nf++)
            acc[nf] = f32x4{0.f, 0.f, 0.f, 0.f};

        #pragma unroll
        for (int ks = 0; ks < KS; ks++) {
            bf16x8 a = *(const bf16x8*)(xrow + ks * 32);
            #pragma unroll
            for (int nf = 0; nf < NFW; nf++)
                acc[nf] = __builtin_amdgcn_mfma_f32_16x16x32_bf16(a, breg[ks][nf], acc[nf], 0, 0, 0);
        }

        // scale by basis, transpose via per-wave LDS slice
        #pragma unroll
        for (int nf = 0; nf < NFW; nf++) {
            #pragma unroll
            for (int r = 0; r < 4; r++) {
                int pl = l4 * 4 + r;
                float bs = __shfl(basv, pl);
                twave[pl * TSTR + nf * 16 + l15] = f2bf(acc[nf][r] * bs);
            }
        }
        asm volatile("s_waitcnt lgkmcnt(0)" ::: "memory");
        __builtin_amdgcn_sched_barrier(0);

        // store: wave writes its own column range of its 16 rows
        #pragma unroll
        for (int it = 0; it < (16 * CHW + 63) / 64; it++) {
            int cid = it * 64 + lane;
            int row = cid / CHW, ch = cid % CHW;
            int srr = __shfl(srv, row);
            if (row < np)
                *(bf16x8*)(mpart + (size_t)srr * OUT16 + wn * TW + ch * 8) =
                    *(const bf16x8*)&twave[row * TSTR + ch * 8];
        }
        __builtin_amdgcn_wave_barrier();
    }
}

// ---------------- wave-per-bucket conv for ks=7 (IN=64, OUT=13) ----------------
__global__ __launch_bounds__(256) void conv_mfma_w7(
    const u16* __restrict__ xbf, const int* __restrict__ src,
    const float* __restrict__ W, const int* __restrict__ offs,
    const int4* __restrict__ pairP, u16* __restrict__ mpart, int K) {
    constexpr int IN = 64, OUT = 13, OUT16 = 16;
    __shared__ u16 WT[4][16 * 72];
    __shared__ u16 tbAll[4][16 * 24];
    int t = threadIdx.x, wid = t >> 6, lane = t & 63;
    int k = blockIdx.x * 4 + wid;
    if (k >= K) return;
    int p0 = offs[k], p1 = offs[k + 1];
    if (p0 >= p1) return;
    u16* tb = tbAll[wid];
    u16* wt = WT[wid];

    int l15 = lane & 15, l4 = lane >> 4;
    const float* Wg = W + (size_t)k * (IN * OUT);
    for (int f = lane; f < IN * OUT; f += 64) {
        int r = f / OUT, c = f - r * OUT;
        wt[c * 72 + r] = f2bf(Wg[f]);
    }
    bf16x8 breg[2];
    #pragma unroll
    for (int ks = 0; ks < 2; ks++)
        breg[ks] = (l15 < OUT) ? *(const bf16x8*)&wt[l15 * 72 + ks * 32 + l4 * 8]
                               : bf16x8{0, 0, 0, 0, 0, 0, 0, 0};

    for (int t0 = p0; t0 < p1; t0 += 16) {
        int np = min(16, p1 - t0);
        int pi = t0 + l15;
        int4 meta = pairP[pi < p1 ? pi : p0];
        float basv = (l15 < np) ? __int_as_float(meta.y) : 0.0f;
        int nodev = src[meta.x];
        int srv = meta.z;
        const u16* xrow = xbf + (size_t)nodev * IN + l4 * 8;
        f32x4 acc = f32x4{0.f, 0.f, 0.f, 0.f};
        #pragma unroll
        for (int ks = 0; ks < 2; ks++) {
            bf16x8 a = *(const bf16x8*)(xrow + ks * 32);
            acc = __builtin_amdgcn_mfma_f32_16x16x32_bf16(a, breg[ks], acc, 0, 0, 0);
        }
        #pragma unroll
        for (int r = 0; r < 4; r++) {
            int pl = l4 * 4 + r;
            float bs = __shfl(basv, pl);
            tb[pl * 24 + l15] = f2bf(acc[r] * bs);
        }
        asm volatile("s_waitcnt lgkmcnt(0)" ::: "memory");
        __builtin_amdgcn_sched_barrier(0);
        {
            int row = lane >> 1, ch = lane & 1;
            int srr = __shfl(srv, row);
            if (lane < np * 2)
                *(bf16x8*)(mpart + (size_t)srr * OUT16 + ch * 8) =
                    *(const bf16x8*)&tb[row * 24 + ch * 8];
        }
        __builtin_amdgcn_wave_barrier();
    }
}

// ---------------- streaming segment reduce (32B loads) + mean + root + bias ----------------
template <int IN, int OUT, int OUT16, bool HEAD>
__global__ __launch_bounds__(256) void reduce_mfma(
    const u16* __restrict__ mpart, const int* __restrict__ eoff,
    const float* __restrict__ xin, const float* __restrict__ Wr,
    const float* __restrict__ bias, float* __restrict__ hout,
    u16* __restrict__ hbf, int N) {
    int n = blockIdx.x;
    int e0 = eoff[n], e1 = eoff[n + 1];
    int R = (e1 - e0) * SCOR;
    size_t rs = (size_t)e0 * SCOR;
    constexpr int CH = OUT16 / 16;   // 32B chunks per row
    constexpr int G = 256 / CH;
    int t = threadIdx.x;
    int ch = t % CH, rg = t / CH;
    float a[16];
    #pragma unroll
    for (int j = 0; j < 16; j++) a[j] = 0.0f;
    #pragma unroll 2
    for (int r = rg; r < R; r += G) {
        const u16* mp = mpart + (rs + r) * OUT16 + ch * 16;
        bf16x8 v0 = *(const bf16x8*)mp;
        bf16x8 v1 = *(const bf16x8*)(mp + 8);
        #pragma unroll
        for (int j = 0; j < 8; j++) a[j] += bf2f(((const u16*)&v0)[j]);
        #pragma unroll
        for (int j = 0; j < 8; j++) a[8 + j] += bf2f(((const u16*)&v1)[j]);
    }
    __shared__ float part[256 * 17];
    #pragma unroll
    for (int j = 0; j < 16; j++) part[t * 17 + j] = a[j];
    __syncthreads();
    for (int h = G / 2; h >= 1; h >>= 1) {
        if (rg < h) {
            #pragma unroll
            for (int j = 0; j < 16; j++)
                part[t * 17 + j] += part[(t + h * CH) * 17 + j];
        }
        __syncthreads();
    }
    __shared__ float sm[16];
    if (t < OUT) {
        float s = part[(t / 16) * 17 + (t % 16)];
        int dg = e1 - e0;
        s /= (dg < 1) ? 1.0f : (float)dg;
        s += bias[t];
        const float* xr = xin + (size_t)n * IN;
        #pragma unroll 8
        for (int i = 0; i < IN; i++) s += xr[i] * Wr[i * OUT + t];
        if constexpr (HEAD) {
            sm[t] = s;
        } else {
            hout[(size_t)n * OUT + t] = s;
            if (hbf) hbf[(size_t)n * OUT + t] = f2bf(s);
        }
    }
    if constexpr (HEAD) {
        __syncthreads();
        if (t < OUT) {
            float v[13];
            float mx = -1e30f;
            #pragma unroll
            for (int c = 0; c < 13; c++) {
                float z = sm[c];
                z = z > 0.0f ? z : (expf(z) - 1.0f);
                v[c] = z;
                mx = fmaxf(mx, z);
            }
            float sum = 0.0f;
            #pragma unroll
            for (int c = 0; c < 13; c++) sum += expf(v[c] - mx);
            float lse = mx + logf(sum);
            hout[(size_t)n * 13 + t] = v[t] - lse;
        }
    }
}

extern "C" void kernel_launch(void* const* d_in, const int* in_sizes, int n_in,
                              void* d_out, int out_size, void* d_ws, size_t ws_size,
                              hipStream_t stream) {
    const float* x   = (const float*)d_in[0];
    const int*   ei  = (const int*)d_in[1];
    const float* ea  = (const float*)d_in[2];
    const float* W1  = (const float*)d_in[3];
    const float* Wr1 = (const float*)d_in[4];
    const float* b1  = (const float*)d_in[5];
    const float* W3  = (const float*)d_in[6];
    const float* Wr3 = (const float*)d_in[7];
    const float* b3  = (const float*)d_in[8];
    const float* W6  = (const float*)d_in[9];
    const float* Wr6 = (const float*)d_in[10];
    const float* b6  = (const float*)d_in[11];
    const float* W7  = (const float*)d_in[12];
    const float* Wr7 = (const float*)d_in[13];
    const float* b7  = (const float*)d_in[14];

    const int N = in_sizes[0] / 32;
    const int E = in_sizes[1] / 2;
    const int* src = ei;
    const int* dst = ei + E;
    (void)n_in; (void)out_size; (void)ws_size;

    const int K3 = 729, K5 = 15625, K7 = 117649;
    const int P = E * SCOR;

    const int BS = 1024;
    const int Np = (N + BS - 1) / BS * BS;
    const int nb0 = Np / BS;
    const int P3 = 1024, P5 = 16384, P7 = 117760;
    const int totalPad = Np + P3 + P5 + P7;
    const int nBlocks = nb0 + 1 + 16 + 115;

    char* ws = (char*)d_ws;
    size_t off = 0;
    auto alloc = [&](size_t bytes) {
        void* p = ws + off;
        off += (bytes + 255) & ~(size_t)255;
        return p;
    };
    int*   zb    = (int*)alloc((size_t)totalPad * 4);
    int*   degi  = zb;
    int*   cnt3  = zb + Np;
    int*   cnt5  = cnt3 + P3;
    int*   cnt7  = cnt5 + P5;
    int*   bsum  = (int*)alloc((size_t)nBlocks * 4);
    int*   eoff  = (int*)alloc((size_t)(N + 1) * 4);
    int*   offs3 = (int*)alloc((size_t)(K3 + 1) * 4);
    int*   offs5 = (int*)alloc((size_t)(K5 + 1) * 4);
    int*   offs7 = (int*)alloc((size_t)(K7 + 1) * 4);
    int4*  pP3   = (int4*)alloc((size_t)P * 16);
    int4*  pP5   = (int4*)alloc((size_t)P * 16);
    int4*  pP7   = (int4*)alloc((size_t)P * 16);
    float* h1    = (float*)alloc((size_t)N * 128 * 4);
    float* h3    = (float*)alloc((size_t)N * 128 * 4);
    float* h6    = (float*)alloc((size_t)N * 64 * 4);
    u16*   xbf1  = (u16*)alloc((size_t)N * 32 * 2);
    u16*   hbf1  = (u16*)alloc((size_t)N * 128 * 2);
    u16*   hbf3  = (u16*)alloc((size_t)N * 128 * 2);
    u16*   hbf6  = (u16*)alloc((size_t)N * 64 * 2);
    u16*   mpart = (u16*)alloc((size_t)P * 128 * 2);  // 256 MiB

    dim3 blk(256);
    dim3 pgrid((P + 255) / 256);

    // zero counters + x -> bf16 (fused)
    int n4 = N * 32 / 4;
    prep_kernel<<<(max(totalPad, n4) + 255) / 256, blk, 0, stream>>>(zb, totalPad, x, xbf1, n4);

    // fused counting (3 ks + degree)
    count_all<<<pgrid, blk, 0, stream>>>(ea, dst, cnt3, cnt5, cnt7, degi, P);

    // parallel segmented scan
    scan_partial<<<nBlocks, blk, 0, stream>>>(zb, bsum);
    scan_final<<<nBlocks, blk, 0, stream>>>(zb, bsum, eoff, offs3, offs5, offs7, N, nb0);

    // fused fill (3 ks + per-edge dst-rank in one pass)
    fill_all<<<pgrid, blk, 0, stream>>>(ea, dst, degi, cnt3, pP3, cnt5, pP5, cnt7, pP7, P);

    // layer 1: 32 -> 128
    conv_mfma_r<32, 128, 8, 2, 2><<<dim3(K3, 2), dim3(512), 0, stream>>>(
        xbf1, src, W1, offs3, pP3, mpart);
    reduce_mfma<32, 128, 128, false><<<N, blk, 0, stream>>>(mpart, eoff, x, Wr1, b1, h1, hbf1, N);

    // layer 3: 128 -> 128
    conv_mfma_r<128, 128, 8, 2, 2><<<dim3(K3, 2), dim3(512), 0, stream>>>(
        hbf1, src, W3, offs3, pP3, mpart);
    reduce_mfma<128, 128, 128, false><<<N, blk, 0, stream>>>(mpart, eoff, h1, Wr3, b3, h3, hbf3, N);

    // layer 6: 128 -> 64
    conv_mfma_r<128, 64, 4, 2, 1><<<dim3(K5, 1), blk, 0, stream>>>(
        hbf3, src, W6, offs5, pP5, mpart);
    reduce_mfma<128, 64, 64, false><<<N, blk, 0, stream>>>(mpart, eoff, h3, Wr6, b6, h6, hbf6, N);

    // layer 7: 64 -> 13 (wave per bucket) + fused ELU/log_softmax head
    conv_mfma_w7<<<(K7 + 3) / 4, blk, 0, stream>>>(hbf6, src, W7, offs7, pP7, mpart, K7);
    reduce_mfma<64, 13, 16, true><<<N, blk, 0, stream>>>(mpart, eoff, h6, Wr7, b7, (float*)d_out, nullptr, N);
}

// Round 10
// 1275.307 us; speedup vs baseline: 1.1869x; 1.1869x over previous
//
#include <hip/hip_runtime.h>
#include <hip/hip_bf16.h>
#include <cstdint>
#include <cstddef>

constexpr int SDIM = 6;
constexpr int SCOR = 64;   // 2^6 corners
typedef unsigned short u16;
typedef __attribute__((ext_vector_type(8))) short bf16x8;
typedef __attribute__((ext_vector_type(4))) float f32x4;

__device__ __forceinline__ float bf2f(u16 h) {
    union { unsigned u; float f; } v; v.u = ((unsigned)h) << 16; return v.f;
}
__device__ __forceinline__ u16 f2bf(float f) {
    union { float f; unsigned u; } v; v.f = f;
    unsigned r = v.u + 0x7fffu + ((v.u >> 16) & 1u);
    return (u16)(r >> 16);
}

template <int KS>
__device__ __forceinline__ void keybasis(const float* u, int s, int& key, float& basis) {
    int idx = 0, str = 1;
    float b = 1.0f;
    #pragma unroll
    for (int d = 0; d < SDIM; d++) {
        float v = u[d] * (KS - 1);
        float fl = floorf(v);
        float fr = v - fl;
        int bit = (s >> d) & 1;
        int pos = (int)fl + bit;
        pos = min(max(pos, 0), KS - 1);
        idx += pos * str;
        str *= KS;
        b *= bit ? fr : (1.0f - fr);
    }
    key = idx;
    basis = b;
}

// ---------------- fused zero + fp32->bf16 ----------------
__global__ __launch_bounds__(256) void prep_kernel(int* __restrict__ zb, int nz,
                                                   const float* __restrict__ xin,
                                                   u16* __restrict__ xbf, int n4) {
    int i = blockIdx.x * blockDim.x + threadIdx.x;
    if (i < nz) zb[i] = 0;
    if (i < n4) {
        float4 v = ((const float4*)xin)[i];
        ushort4 o;
        o.x = f2bf(v.x); o.y = f2bf(v.y); o.z = f2bf(v.z); o.w = f2bf(v.w);
        ((ushort4*)xbf)[i] = o;
    }
}

// ---------------- fused counting: 3 kernel sizes + degree ----------------
__global__ __launch_bounds__(256) void count_all(const float* __restrict__ ea,
                                                 const int* __restrict__ dst,
                                                 int* __restrict__ cnt3,
                                                 int* __restrict__ cnt5,
                                                 int* __restrict__ cnt7,
                                                 int* __restrict__ degi, int P) {
    int gid = blockIdx.x * blockDim.x + threadIdx.x;
    if (gid >= P) return;
    int e = gid >> 6, s = gid & 63;
    float u[SDIM];
    #pragma unroll
    for (int d = 0; d < SDIM; d++) u[d] = ea[e * SDIM + d];
    int k; float b;
    keybasis<3>(u, s, k, b); atomicAdd(&cnt3[k], 1);
    keybasis<5>(u, s, k, b); atomicAdd(&cnt5[k], 1);
    keybasis<7>(u, s, k, b); atomicAdd(&cnt7[k], 1);
    if (s == 0) atomicAdd(&degi[dst[e]], 1);
}

// ---------------- parallel segmented scan over zb = [deg|cnt3|cnt5|cnt7] ----------------
__global__ __launch_bounds__(256) void scan_partial(const int* __restrict__ zb,
                                                    int* __restrict__ bsum) {
    int b = blockIdx.x, t = threadIdx.x;
    int4 v = *(const int4*)(zb + b * 1024 + t * 4);
    __shared__ int red[256];
    red[t] = v.x + v.y + v.z + v.w;
    __syncthreads();
    for (int h = 128; h >= 1; h >>= 1) {
        if (t < h) red[t] += red[t + h];
        __syncthreads();
    }
    if (t == 0) bsum[b] = red[0];
}

__global__ __launch_bounds__(256) void scan_final(int* __restrict__ zb,
                                                  const int* __restrict__ bsum,
                                                  int* __restrict__ eoff,
                                                  int* __restrict__ offs3,
                                                  int* __restrict__ offs5,
                                                  int* __restrict__ offs7,
                                                  int Nn, int nb0) {
    int b = blockIdx.x, t = threadIdx.x;
    int s1 = nb0, s2 = nb0 + 1, s3 = nb0 + 17;
    int seg = (b >= s3) ? 3 : (b >= s2) ? 2 : (b >= s1) ? 1 : 0;
    int sb = (seg == 0) ? 0 : (seg == 1) ? s1 : (seg == 2) ? s2 : s3;
    int L = (seg == 0) ? Nn : (seg == 1) ? 729 : (seg == 2) ? 15625 : 117649;
    int* offs = (seg == 0) ? eoff : (seg == 1) ? offs3 : (seg == 2) ? offs5 : offs7;

    __shared__ int red[256];
    int cnt = b - sb;
    int acc = 0;
    for (int j = t; j < cnt; j += 256) acc += bsum[sb + j];
    red[t] = acc;
    __syncthreads();
    for (int h = 128; h >= 1; h >>= 1) {
        if (t < h) red[t] += red[t + h];
        __syncthreads();
    }
    int blockPrefix = red[0];
    __syncthreads();

    int idx = b * 1024 + t * 4;
    int4 v = *(const int4*)(zb + idx);
    int tsum = v.x + v.y + v.z + v.w;
    __shared__ int ss[256];
    ss[t] = tsum;
    __syncthreads();
    for (int off = 1; off < 256; off <<= 1) {
        int val = (t >= off) ? ss[t - off] : 0;
        __syncthreads();
        ss[t] += val;
        __syncthreads();
    }
    int p = blockPrefix + ((t == 0) ? 0 : ss[t - 1]);
    int pe[4];
    pe[0] = p;
    pe[1] = p + v.x;
    pe[2] = pe[1] + v.y;
    pe[3] = pe[2] + v.z;
    int vv[4] = {v.x, v.y, v.z, v.w};
    int li = (b - sb) * 1024 + t * 4;
    #pragma unroll
    for (int j = 0; j < 4; j++) {
        int gi = li + j;
        if (gi < L) {
            offs[gi] = pe[j];
            zb[idx + j] = pe[j];   // cursor init
            if (gi == L - 1) offs[L] = pe[j] + vv[j];
        }
    }
}

// ---------------- fused fill: one wave = one edge; lane = corner ----------------
// meta = {node=src[e], basis, er64, 0} -> conv needs no src indirection.
__global__ __launch_bounds__(256) void fill_all(const float* __restrict__ ea,
                                                const int* __restrict__ src,
                                                const int* __restrict__ dst,
                                                int* __restrict__ ecur,
                                                int* __restrict__ cur3, int4* __restrict__ pP3,
                                                int* __restrict__ cur5, int4* __restrict__ pP5,
                                                int* __restrict__ cur7, int4* __restrict__ pP7,
                                                int P) {
    int gid = blockIdx.x * blockDim.x + threadIdx.x;
    if (gid >= P) return;
    int e = gid >> 6;
    int lane = threadIdx.x & 63;   // == corner s
    float u[SDIM];
    #pragma unroll
    for (int d = 0; d < SDIM; d++) u[d] = ea[e * SDIM + d];
    int node = src[e];
    int er = 0;
    if (lane == 0) er = atomicAdd(&ecur[dst[e]], 1);
    er = __shfl(er, 0);
    int er64 = er * SCOR + lane;
    int k; float b; int slot;
    keybasis<3>(u, lane, k, b);
    slot = atomicAdd(&cur3[k], 1);
    pP3[slot] = make_int4(node, __float_as_int(b), er64, 0);
    keybasis<5>(u, lane, k, b);
    slot = atomicAdd(&cur5[k], 1);
    pP5[slot] = make_int4(node, __float_as_int(b), er64, 0);
    keybasis<7>(u, lane, k, b);
    slot = atomicAdd(&cur7[k], 1);
    pP7[slot] = make_int4(node, __float_as_int(b), er64, 0);
}

// ---------------- MFMA bucketed conv ----------------
// W[k]: coalesced global -> row-major LDS (linear, conflict-free) -> one-time
// per-wave scalar reads into B-fragment registers. Main loop: barrier-free
// per-wave 16-pair tiles with 1-deep prefetch of metadata + A-fragments.
template <int IN, int OUT, int WAVES, int WN, int GY>
__global__ __launch_bounds__(WAVES * 64) void conv_mfma_r(
    const u16* __restrict__ xbf, const float* __restrict__ W,
    const int* __restrict__ offs, const int4* __restrict__ pairP,
    u16* __restrict__ mpart) {
    constexpr int NT = WAVES * 64;
    constexpr int WM = WAVES / WN;
    constexpr int OUT16 = (OUT + 15) & ~15;
    static_assert(OUT == OUT16, "conv_mfma_r requires OUT multiple of 16");
    constexpr int NF = OUT16 / 16;
    constexpr int NFW = NF / WN;
    constexpr int KS = IN / 32;
    constexpr int TW = NFW * 16;
    constexpr int TSTR = TW + 8;
    constexpr int CHW = TW / 8;
    static_assert((TSTR * 2) % 16 == 0, "row stride must be 16B aligned");
    static_assert((IN * OUT) % NT == 0, "staging divisibility");

    __shared__ u16 Wlds[IN * OUT];
    __shared__ u16 tall[WAVES][16 * TSTR];

    int k = blockIdx.x;
    int p0 = offs[k], p1 = offs[k + 1];
    int t = threadIdx.x;
    int wid = t >> 6, lane = t & 63;
    int wm = wid % WM, wn = wid / WM;
    int l15 = lane & 15, l4 = lane >> 4;
    u16* twave = tall[wid];

    if (p0 + (int)blockIdx.y * WM * 16 >= p1) return;

    // stage W[k]: coalesced fp32 -> bf16, row-major linear LDS (no conflicts)
    const float* Wg = W + (size_t)k * IN * OUT;
    #pragma unroll
    for (int f0 = 0; f0 < IN * OUT; f0 += NT)
        Wlds[f0 + t] = f2bf(Wg[f0 + t]);
    __syncthreads();

    // one-time scalar assembly of B fragments (2B-stride reads -> bank-spread)
    bf16x8 breg[KS][NFW];
    #pragma unroll
    for (int ks = 0; ks < KS; ks++) {
        #pragma unroll
        for (int nf = 0; nf < NFW; nf++) {
            int col = (wn * NFW + nf) * 16 + l15;
            int rbase = ks * 32 + l4 * 8;
            bf16x8 b;
            #pragma unroll
            for (int j = 0; j < 8; j++)
                ((u16*)&b)[j] = Wlds[(rbase + j) * OUT + col];
            breg[ks][nf] = b;
        }
    }

    constexpr int STRIDE = WM * GY * 16;
    int t0 = p0 + ((int)blockIdx.y * WM + wm) * 16;
    if (t0 >= p1) return;

    // prologue: load tile t0 metadata + A fragments
    int4 meta = pairP[min(t0 + l15, p1 - 1)];
    bf16x8 a[KS];
    {
        const u16* xrow = xbf + (size_t)meta.x * IN + l4 * 8;
        #pragma unroll
        for (int ks = 0; ks < KS; ks++) a[ks] = *(const bf16x8*)(xrow + ks * 32);
    }

    while (true) {
        int np = min(16, p1 - t0);
        float basv = (l15 < np) ? __int_as_float(meta.y) : 0.0f;
        int srv = meta.z;
        int tn = t0 + STRIDE;
        bool has = tn < p1;
        int4 metaN = meta;
        if (has) metaN = pairP[min(tn + l15, p1 - 1)];   // issue early

        f32x4 acc[NFW];
        #pragma unroll
        for (int nf = 0; nf < NFW; nf++)
            acc[nf] = f32x4{0.f, 0.f, 0.f, 0.f};
        #pragma unroll
        for (int ks = 0; ks < KS; ks++) {
            #pragma unroll
            for (int nf = 0; nf < NFW; nf++)
                acc[nf] = __builtin_amdgcn_mfma_f32_16x16x32_bf16(a[ks], breg[ks][nf], acc[nf], 0, 0, 0);
        }

        // issue next tile's A loads (hidden under transpose + store)
        bf16x8 aN[KS];
        if (has) {
            const u16* xrowN = xbf + (size_t)metaN.x * IN + l4 * 8;
            #pragma unroll
            for (int ks = 0; ks < KS; ks++) aN[ks] = *(const bf16x8*)(xrowN + ks * 32);
        }

        // scale by basis, transpose via per-wave LDS slice
        #pragma unroll
        for (int nf = 0; nf < NFW; nf++) {
            #pragma unroll
            for (int r = 0; r < 4; r++) {
                int pl = l4 * 4 + r;
                float bs = __shfl(basv, pl);
                twave[pl * TSTR + nf * 16 + l15] = f2bf(acc[nf][r] * bs);
            }
        }

        // store: wave writes its own column range of its 16 rows (dst-sorted)
        #pragma unroll
        for (int it = 0; it < (16 * CHW + 63) / 64; it++) {
            int cid = it * 64 + lane;
            int row = cid / CHW, ch = cid % CHW;
            int srr = __shfl(srv, row);
            if (row < np)
                *(bf16x8*)(mpart + (size_t)srr * OUT16 + wn * TW + ch * 8) =
                    *(const bf16x8*)&twave[row * TSTR + ch * 8];
        }

        if (!has) break;
        t0 = tn;
        meta = metaN;
        #pragma unroll
        for (int ks = 0; ks < KS; ks++) a[ks] = aN[ks];
    }
}

// ---------------- wave-per-bucket conv for ks=7 (IN=64, OUT=13) ----------------
__global__ __launch_bounds__(256) void conv_mfma_w7(
    const u16* __restrict__ xbf, const float* __restrict__ W,
    const int* __restrict__ offs, const int4* __restrict__ pairP,
    u16* __restrict__ mpart, int K) {
    constexpr int IN = 64, OUT = 13, OUT16 = 16;
    __shared__ u16 WT[4][16 * 72];
    __shared__ u16 tbAll[4][16 * 24];
    int t = threadIdx.x, wid = t >> 6, lane = t & 63;
    int k = blockIdx.x * 4 + wid;
    if (k >= K) return;
    int p0 = offs[k], p1 = offs[k + 1];
    if (p0 >= p1) return;
    u16* tb = tbAll[wid];
    u16* wt = WT[wid];

    int l15 = lane & 15, l4 = lane >> 4;
    const float* Wg = W + (size_t)k * (IN * OUT);
    for (int f = lane; f < IN * OUT; f += 64) {
        int r = f / OUT, c = f - r * OUT;
        wt[c * 72 + r] = f2bf(Wg[f]);
    }
    bf16x8 breg[2];
    #pragma unroll
    for (int ks = 0; ks < 2; ks++)
        breg[ks] = (l15 < OUT) ? *(const bf16x8*)&wt[l15 * 72 + ks * 32 + l4 * 8]
                               : bf16x8{0, 0, 0, 0, 0, 0, 0, 0};

    for (int t0 = p0; t0 < p1; t0 += 16) {
        int np = min(16, p1 - t0);
        int4 meta = pairP[min(t0 + l15, p1 - 1)];
        float basv = (l15 < np) ? __int_as_float(meta.y) : 0.0f;
        int srv = meta.z;
        const u16* xrow = xbf + (size_t)meta.x * IN + l4 * 8;
        f32x4 acc = f32x4{0.f, 0.f, 0.f, 0.f};
        #pragma unroll
        for (int ks = 0; ks < 2; ks++) {
            bf16x8 a = *(const bf16x8*)(xrow + ks * 32);
            acc = __builtin_amdgcn_mfma_f32_16x16x32_bf16(a, breg[ks], acc, 0, 0, 0);
        }
        #pragma unroll
        for (int r = 0; r < 4; r++) {
            int pl = l4 * 4 + r;
            float bs = __shfl(basv, pl);
            tb[pl * 24 + l15] = f2bf(acc[r] * bs);
        }
        {
            int row = lane >> 1, ch = lane & 1;
            int srr = __shfl(srv, row);
            if (lane < np * 2)
                *(bf16x8*)(mpart + (size_t)srr * OUT16 + ch * 8) =
                    *(const bf16x8*)&tb[row * 24 + ch * 8];
        }
    }
}

// ---------------- streaming segment reduce (32B loads) + mean + root + bias ----------------
template <int IN, int OUT, int OUT16, bool HEAD>
__global__ __launch_bounds__(256) void reduce_mfma(
    const u16* __restrict__ mpart, const int* __restrict__ eoff,
    const float* __restrict__ xin, const float* __restrict__ Wr,
    const float* __restrict__ bias, float* __restrict__ hout,
    u16* __restrict__ hbf, int N) {
    int n = blockIdx.x;
    int e0 = eoff[n], e1 = eoff[n + 1];
    int R = (e1 - e0) * SCOR;
    size_t rs = (size_t)e0 * SCOR;
    constexpr int CH = OUT16 / 16;   // 32B chunks per row
    constexpr int G = 256 / CH;
    int t = threadIdx.x;
    int ch = t % CH, rg = t / CH;
    float a[16];
    #pragma unroll
    for (int j = 0; j < 16; j++) a[j] = 0.0f;
    #pragma unroll 2
    for (int r = rg; r < R; r += G) {
        const u16* mp = mpart + (rs + r) * OUT16 + ch * 16;
        bf16x8 v0 = *(const bf16x8*)mp;
        bf16x8 v1 = *(const bf16x8*)(mp + 8);
        #pragma unroll
        for (int j = 0; j < 8; j++) a[j] += bf2f(((const u16*)&v0)[j]);
        #pragma unroll
        for (int j = 0; j < 8; j++) a[8 + j] += bf2f(((const u16*)&v1)[j]);
    }
    __shared__ float part[256 * 17];
    #pragma unroll
    for (int j = 0; j < 16; j++) part[t * 17 + j] = a[j];
    __syncthreads();
    for (int h = G / 2; h >= 1; h >>= 1) {
        if (rg < h) {
            #pragma unroll
            for (int j = 0; j < 16; j++)
                part[t * 17 + j] += part[(t + h * CH) * 17 + j];
        }
        __syncthreads();
    }
    __shared__ float sm[16];
    if (t < OUT) {
        float s = part[(t / 16) * 17 + (t % 16)];
        int dg = e1 - e0;
        s /= (dg < 1) ? 1.0f : (float)dg;
        s += bias[t];
        const float* xr = xin + (size_t)n * IN;
        #pragma unroll 8
        for (int i = 0; i < IN; i++) s += xr[i] * Wr[i * OUT + t];
        if constexpr (HEAD) {
            sm[t] = s;
        } else {
            hout[(size_t)n * OUT + t] = s;
            if (hbf) hbf[(size_t)n * OUT + t] = f2bf(s);
        }
    }
    if constexpr (HEAD) {
        __syncthreads();
        if (t < OUT) {
            float v[13];
            float mx = -1e30f;
            #pragma unroll
            for (int c = 0; c < 13; c++) {
                float z = sm[c];
                z = z > 0.0f ? z : (expf(z) - 1.0f);
                v[c] = z;
                mx = fmaxf(mx, z);
            }
            float sum = 0.0f;
            #pragma unroll
            for (int c = 0; c < 13; c++) sum += expf(v[c] - mx);
            float lse = mx + logf(sum);
            hout[(size_t)n * 13 + t] = v[t] - lse;
        }
    }
}

extern "C" void kernel_launch(void* const* d_in, const int* in_sizes, int n_in,
                              void* d_out, int out_size, void* d_ws, size_t ws_size,
                              hipStream_t stream) {
    const float* x   = (const float*)d_in[0];
    const int*   ei  = (const int*)d_in[1];
    const float* ea  = (const float*)d_in[2];
    const float* W1  = (const float*)d_in[3];
    const float* Wr1 = (const float*)d_in[4];
    const float* b1  = (const float*)d_in[5];
    const float* W3  = (const float*)d_in[6];
    const float* Wr3 = (const float*)d_in[7];
    const float* b3  = (const float*)d_in[8];
    const float* W6  = (const float*)d_in[9];
    const float* Wr6 = (const float*)d_in[10];
    const float* b6  = (const float*)d_in[11];
    const float* W7  = (const float*)d_in[12];
    const float* Wr7 = (const float*)d_in[13];
    const float* b7  = (const float*)d_in[14];

    const int N = in_sizes[0] / 32;
    const int E = in_sizes[1] / 2;
    const int* src = ei;
    const int* dst = ei + E;
    (void)n_in; (void)out_size; (void)ws_size;

    const int K3 = 729, K5 = 15625, K7 = 117649;
    const int P = E * SCOR;

    const int BS = 1024;
    const int Np = (N + BS - 1) / BS * BS;
    const int nb0 = Np / BS;
    const int P3 = 1024, P5 = 16384, P7 = 117760;
    const int totalPad = Np + P3 + P5 + P7;
    const int nBlocks = nb0 + 1 + 16 + 115;

    char* ws = (char*)d_ws;
    size_t off = 0;
    auto alloc = [&](size_t bytes) {
        void* p = ws + off;
        off += (bytes + 255) & ~(size_t)255;
        return p;
    };
    int*   zb    = (int*)alloc((size_t)totalPad * 4);
    int*   degi  = zb;
    int*   cnt3  = zb + Np;
    int*   cnt5  = cnt3 + P3;
    int*   cnt7  = cnt5 + P5;
    int*   bsum  = (int*)alloc((size_t)nBlocks * 4);
    int*   eoff  = (int*)alloc((size_t)(N + 1) * 4);
    int*   offs3 = (int*)alloc((size_t)(K3 + 1) * 4);
    int*   offs5 = (int*)alloc((size_t)(K5 + 1) * 4);
    int*   offs7 = (int*)alloc((size_t)(K7 + 1) * 4);
    int4*  pP3   = (int4*)alloc((size_t)P * 16);
    int4*  pP5   = (int4*)alloc((size_t)P * 16);
    int4*  pP7   = (int4*)alloc((size_t)P * 16);
    float* h1    = (float*)alloc((size_t)N * 128 * 4);
    float* h3    = (float*)alloc((size_t)N * 128 * 4);
    float* h6    = (float*)alloc((size_t)N * 64 * 4);
    u16*   xbf1  = (u16*)alloc((size_t)N * 32 * 2);
    u16*   hbf1  = (u16*)alloc((size_t)N * 128 * 2);
    u16*   hbf3  = (u16*)alloc((size_t)N * 128 * 2);
    u16*   hbf6  = (u16*)alloc((size_t)N * 64 * 2);
    u16*   mpart = (u16*)alloc((size_t)P * 128 * 2);  // 256 MiB

    dim3 blk(256);
    dim3 pgrid((P + 255) / 256);

    // zero counters + x -> bf16 (fused)
    int n4 = N * 32 / 4;
    prep_kernel<<<(max(totalPad, n4) + 255) / 256, blk, 0, stream>>>(zb, totalPad, x, xbf1, n4);

    // fused counting (3 ks + degree)
    count_all<<<pgrid, blk, 0, stream>>>(ea, dst, cnt3, cnt5, cnt7, degi, P);

    // parallel segmented scan
    scan_partial<<<nBlocks, blk, 0, stream>>>(zb, bsum);
    scan_final<<<nBlocks, blk, 0, stream>>>(zb, bsum, eoff, offs3, offs5, offs7, N, nb0);

    // fused fill (3 ks + per-edge dst-rank, node stored in metadata)
    fill_all<<<pgrid, blk, 0, stream>>>(ea, src, dst, degi, cnt3, pP3, cnt5, pP5, cnt7, pP7, P);

    // layer 1: 32 -> 128
    conv_mfma_r<32, 128, 8, 2, 4><<<dim3(K3, 4), dim3(512), 0, stream>>>(
        xbf1, W1, offs3, pP3, mpart);
    reduce_mfma<32, 128, 128, false><<<N, blk, 0, stream>>>(mpart, eoff, x, Wr1, b1, h1, hbf1, N);

    // layer 3: 128 -> 128
    conv_mfma_r<128, 128, 8, 2, 8><<<dim3(K3, 8), dim3(512), 0, stream>>>(
        hbf1, W3, offs3, pP3, mpart);
    reduce_mfma<128, 128, 128, false><<<N, blk, 0, stream>>>(mpart, eoff, h1, Wr3, b3, h3, hbf3, N);

    // layer 6: 128 -> 64
    conv_mfma_r<128, 64, 4, 2, 1><<<dim3(K5, 1), blk, 0, stream>>>(
        hbf3, W6, offs5, pP5, mpart);
    reduce_mfma<128, 64, 64, false><<<N, blk, 0, stream>>>(mpart, eoff, h3, Wr6, b6, h6, hbf6, N);

    // layer 7: 64 -> 13 (wave per bucket) + fused ELU/log_softmax head
    conv_mfma_w7<<<(K7 + 3) / 4, blk, 0, stream>>>(hbf6, W7, offs7, pP7, mpart, K7);
    reduce_mfma<64, 13, 16, true><<<N, blk, 0, stream>>>(mpart, eoff, h6, Wr7, b7, (float*)d_out, nullptr, N);
}

// Round 11
// 1261.957 us; speedup vs baseline: 1.1995x; 1.0106x over previous
//
#include <hip/hip_runtime.h>
#include <hip/hip_bf16.h>
#include <cstdint>
#include <cstddef>

constexpr int SDIM = 6;
constexpr int SCOR = 64;   // 2^6 corners
typedef unsigned short u16;
typedef __attribute__((ext_vector_type(8))) short bf16x8;
typedef __attribute__((ext_vector_type(4))) float f32x4;

__device__ __forceinline__ float bf2f(u16 h) {
    union { unsigned u; float f; } v; v.u = ((unsigned)h) << 16; return v.f;
}
__device__ __forceinline__ u16 f2bf(float f) {
    union { float f; unsigned u; } v; v.f = f;
    unsigned r = v.u + 0x7fffu + ((v.u >> 16) & 1u);
    return (u16)(r >> 16);
}

template <int KS>
__device__ __forceinline__ void keybasis(const float* u, int s, int& key, float& basis) {
    int idx = 0, str = 1;
    float b = 1.0f;
    #pragma unroll
    for (int d = 0; d < SDIM; d++) {
        float v = u[d] * (KS - 1);
        float fl = floorf(v);
        float fr = v - fl;
        int bit = (s >> d) & 1;
        int pos = (int)fl + bit;
        pos = min(max(pos, 0), KS - 1);
        idx += pos * str;
        str *= KS;
        b *= bit ? fr : (1.0f - fr);
    }
    key = idx;
    basis = b;
}

// ---------------- fused zero + fp32->bf16 ----------------
__global__ __launch_bounds__(256) void prep_kernel(int* __restrict__ zb, int nz,
                                                   const float* __restrict__ xin,
                                                   u16* __restrict__ xbf, int n4) {
    int i = blockIdx.x * blockDim.x + threadIdx.x;
    if (i < nz) zb[i] = 0;
    if (i < n4) {
        float4 v = ((const float4*)xin)[i];
        ushort4 o;
        o.x = f2bf(v.x); o.y = f2bf(v.y); o.z = f2bf(v.z); o.w = f2bf(v.w);
        ((ushort4*)xbf)[i] = o;
    }
}

// ---------------- fused counting: 3 kernel sizes + degree ----------------
__global__ __launch_bounds__(256) void count_all(const float* __restrict__ ea,
                                                 const int* __restrict__ dst,
                                                 int* __restrict__ cnt3,
                                                 int* __restrict__ cnt5,
                                                 int* __restrict__ cnt7,
                                                 int* __restrict__ degi, int P) {
    int gid = blockIdx.x * blockDim.x + threadIdx.x;
    if (gid >= P) return;
    int e = gid >> 6, s = gid & 63;
    float u[SDIM];
    #pragma unroll
    for (int d = 0; d < SDIM; d++) u[d] = ea[e * SDIM + d];
    int k; float b;
    keybasis<3>(u, s, k, b); atomicAdd(&cnt3[k], 1);
    keybasis<5>(u, s, k, b); atomicAdd(&cnt5[k], 1);
    keybasis<7>(u, s, k, b); atomicAdd(&cnt7[k], 1);
    if (s == 0) atomicAdd(&degi[dst[e]], 1);
}

// ---------------- parallel segmented scan over zb = [deg|cnt3|cnt5|cnt7] ----------------
__global__ __launch_bounds__(256) void scan_partial(const int* __restrict__ zb,
                                                    int* __restrict__ bsum) {
    int b = blockIdx.x, t = threadIdx.x;
    int4 v = *(const int4*)(zb + b * 1024 + t * 4);
    __shared__ int red[256];
    red[t] = v.x + v.y + v.z + v.w;
    __syncthreads();
    for (int h = 128; h >= 1; h >>= 1) {
        if (t < h) red[t] += red[t + h];
        __syncthreads();
    }
    if (t == 0) bsum[b] = red[0];
}

__global__ __launch_bounds__(256) void scan_final(int* __restrict__ zb,
                                                  const int* __restrict__ bsum,
                                                  int* __restrict__ eoff,
                                                  int* __restrict__ offs3,
                                                  int* __restrict__ offs5,
                                                  int* __restrict__ offs7,
                                                  int Nn, int nb0) {
    int b = blockIdx.x, t = threadIdx.x;
    int s1 = nb0, s2 = nb0 + 1, s3 = nb0 + 17;
    int seg = (b >= s3) ? 3 : (b >= s2) ? 2 : (b >= s1) ? 1 : 0;
    int sb = (seg == 0) ? 0 : (seg == 1) ? s1 : (seg == 2) ? s2 : s3;
    int L = (seg == 0) ? Nn : (seg == 1) ? 729 : (seg == 2) ? 15625 : 117649;
    int* offs = (seg == 0) ? eoff : (seg == 1) ? offs3 : (seg == 2) ? offs5 : offs7;

    __shared__ int red[256];
    int cnt = b - sb;
    int acc = 0;
    for (int j = t; j < cnt; j += 256) acc += bsum[sb + j];
    red[t] = acc;
    __syncthreads();
    for (int h = 128; h >= 1; h >>= 1) {
        if (t < h) red[t] += red[t + h];
        __syncthreads();
    }
    int blockPrefix = red[0];
    __syncthreads();

    int idx = b * 1024 + t * 4;
    int4 v = *(const int4*)(zb + idx);
    int tsum = v.x + v.y + v.z + v.w;
    __shared__ int ss[256];
    ss[t] = tsum;
    __syncthreads();
    for (int off = 1; off < 256; off <<= 1) {
        int val = (t >= off) ? ss[t - off] : 0;
        __syncthreads();
        ss[t] += val;
        __syncthreads();
    }
    int p = blockPrefix + ((t == 0) ? 0 : ss[t - 1]);
    int pe[4];
    pe[0] = p;
    pe[1] = p + v.x;
    pe[2] = pe[1] + v.y;
    pe[3] = pe[2] + v.z;
    int vv[4] = {v.x, v.y, v.z, v.w};
    int li = (b - sb) * 1024 + t * 4;
    #pragma unroll
    for (int j = 0; j < 4; j++) {
        int gi = li + j;
        if (gi < L) {
            offs[gi] = pe[j];
            zb[idx + j] = pe[j];   // cursor init
            if (gi == L - 1) offs[L] = pe[j] + vv[j];
        }
    }
}

// ---------------- fused fill: one wave = one edge; lane = corner ----------------
__global__ __launch_bounds__(256) void fill_all(const float* __restrict__ ea,
                                                const int* __restrict__ src,
                                                const int* __restrict__ dst,
                                                int* __restrict__ ecur,
                                                int* __restrict__ cur3, int4* __restrict__ pP3,
                                                int* __restrict__ cur5, int4* __restrict__ pP5,
                                                int* __restrict__ cur7, int4* __restrict__ pP7,
                                                int P) {
    int gid = blockIdx.x * blockDim.x + threadIdx.x;
    if (gid >= P) return;
    int e = gid >> 6;
    int lane = threadIdx.x & 63;   // == corner s
    float u[SDIM];
    #pragma unroll
    for (int d = 0; d < SDIM; d++) u[d] = ea[e * SDIM + d];
    int node = src[e];
    int er = 0;
    if (lane == 0) er = atomicAdd(&ecur[dst[e]], 1);
    er = __shfl(er, 0);
    int er64 = er * SCOR + lane;
    int k; float b; int slot;
    keybasis<3>(u, lane, k, b);
    slot = atomicAdd(&cur3[k], 1);
    pP3[slot] = make_int4(node, __float_as_int(b), er64, 0);
    keybasis<5>(u, lane, k, b);
    slot = atomicAdd(&cur5[k], 1);
    pP5[slot] = make_int4(node, __float_as_int(b), er64, 0);
    keybasis<7>(u, lane, k, b);
    slot = atomicAdd(&cur7[k], 1);
    pP7[slot] = make_int4(node, __float_as_int(b), er64, 0);
}

// ---------------- MFMA bucketed conv ----------------
// W[k]: coalesced global -> padded row-major LDS (stride OUT+2: conflict-free
// on both the linear staging writes and the strided breg assembly reads) ->
// one-time per-wave B-fragment registers. Main loop: barrier-free per-wave
// 16-pair tiles, 1-deep prefetch, nontemporal mpart stores.
template <int IN, int OUT, int WAVES, int WN, int GY>
__global__ __launch_bounds__(WAVES * 64) void conv_mfma_r(
    const u16* __restrict__ xbf, const float* __restrict__ W,
    const int* __restrict__ offs, const int4* __restrict__ pairP,
    u16* __restrict__ mpart) {
    constexpr int NT = WAVES * 64;
    constexpr int WM = WAVES / WN;
    constexpr int OUT16 = (OUT + 15) & ~15;
    static_assert(OUT == OUT16, "conv_mfma_r requires OUT multiple of 16");
    constexpr int WSTR = OUT + 2;    // padded LDS row stride (65 dw mod 32 = 1)
    constexpr int NF = OUT16 / 16;
    constexpr int NFW = NF / WN;
    constexpr int KS = IN / 32;
    constexpr int TW = NFW * 16;
    constexpr int TSTR = TW + 8;
    constexpr int CHW = TW / 8;
    static_assert((TSTR * 2) % 16 == 0, "row stride must be 16B aligned");
    static_assert((IN * OUT) % NT == 0, "staging divisibility");

    __shared__ u16 Wlds[IN * WSTR];
    __shared__ u16 tall[WAVES][16 * TSTR];

    int k = blockIdx.x;
    int p0 = offs[k], p1 = offs[k + 1];
    int t = threadIdx.x;
    int wid = t >> 6, lane = t & 63;
    int wm = wid % WM, wn = wid / WM;
    int l15 = lane & 15, l4 = lane >> 4;
    u16* twave = tall[wid];

    if (p0 + (int)blockIdx.y * WM * 16 >= p1) return;

    // stage W[k]: coalesced fp32 -> bf16, padded row-major LDS
    const float* Wg = W + (size_t)k * IN * OUT;
    #pragma unroll
    for (int f0 = 0; f0 < IN * OUT; f0 += NT) {
        int f = f0 + t;
        int i = f / OUT, o = f % OUT;   // OUT is a power of two -> shifts
        Wlds[i * WSTR + o] = f2bf(Wg[f]);
    }
    __syncthreads();

    // one-time assembly of B fragments (stride 65 dw -> bank-spread, conflict-free)
    bf16x8 breg[KS][NFW];
    #pragma unroll
    for (int ks = 0; ks < KS; ks++) {
        #pragma unroll
        for (int nf = 0; nf < NFW; nf++) {
            int col = (wn * NFW + nf) * 16 + l15;
            int rbase = ks * 32 + l4 * 8;
            bf16x8 b;
            #pragma unroll
            for (int j = 0; j < 8; j++)
                ((u16*)&b)[j] = Wlds[(rbase + j) * WSTR + col];
            breg[ks][nf] = b;
        }
    }

    constexpr int STRIDE = WM * GY * 16;
    int t0 = p0 + ((int)blockIdx.y * WM + wm) * 16;
    if (t0 >= p1) return;

    // prologue: load tile t0 metadata + A fragments
    int4 meta = pairP[min(t0 + l15, p1 - 1)];
    bf16x8 a[KS];
    {
        const u16* xrow = xbf + (size_t)meta.x * IN + l4 * 8;
        #pragma unroll
        for (int ks = 0; ks < KS; ks++) a[ks] = *(const bf16x8*)(xrow + ks * 32);
    }

    while (true) {
        int np = min(16, p1 - t0);
        float basv = (l15 < np) ? __int_as_float(meta.y) : 0.0f;
        int srv = meta.z;
        int tn = t0 + STRIDE;
        bool has = tn < p1;
        int4 metaN = meta;
        if (has) metaN = pairP[min(tn + l15, p1 - 1)];   // issue early

        f32x4 acc[NFW];
        #pragma unroll
        for (int nf = 0; nf < NFW; nf++)
            acc[nf] = f32x4{0.f, 0.f, 0.f, 0.f};
        #pragma unroll
        for (int ks = 0; ks < KS; ks++) {
            #pragma unroll
            for (int nf = 0; nf < NFW; nf++)
                acc[nf] = __builtin_amdgcn_mfma_f32_16x16x32_bf16(a[ks], breg[ks][nf], acc[nf], 0, 0, 0);
        }

        // issue next tile's A loads (hidden under transpose + store)
        bf16x8 aN[KS];
        if (has) {
            const u16* xrowN = xbf + (size_t)metaN.x * IN + l4 * 8;
            #pragma unroll
            for (int ks = 0; ks < KS; ks++) aN[ks] = *(const bf16x8*)(xrowN + ks * 32);
        }

        // scale by basis, transpose via per-wave LDS slice
        #pragma unroll
        for (int nf = 0; nf < NFW; nf++) {
            #pragma unroll
            for (int r = 0; r < 4; r++) {
                int pl = l4 * 4 + r;
                float bs = __shfl(basv, pl);
                twave[pl * TSTR + nf * 16 + l15] = f2bf(acc[nf][r] * bs);
            }
        }

        // store: wave writes its own column range of its 16 rows (dst-sorted)
        #pragma unroll
        for (int it = 0; it < (16 * CHW + 63) / 64; it++) {
            int cid = it * 64 + lane;
            int row = cid / CHW, ch = cid % CHW;
            int srr = __shfl(srv, row);
            if (row < np)
                __builtin_nontemporal_store(
                    *(const bf16x8*)&twave[row * TSTR + ch * 8],
                    (bf16x8*)(mpart + (size_t)srr * OUT16 + wn * TW + ch * 8));
        }

        if (!has) break;
        t0 = tn;
        meta = metaN;
        #pragma unroll
        for (int ks = 0; ks < KS; ks++) a[ks] = aN[ks];
    }
}

// ---------------- wave-per-bucket conv for ks=7 (IN=64, OUT=13) ----------------
__global__ __launch_bounds__(256) void conv_mfma_w7(
    const u16* __restrict__ xbf, const float* __restrict__ W,
    const int* __restrict__ offs, const int4* __restrict__ pairP,
    u16* __restrict__ mpart, int K) {
    constexpr int IN = 64, OUT = 13, OUT16 = 16;
    __shared__ u16 WT[4][16 * 72];
    __shared__ u16 tbAll[4][16 * 24];
    int t = threadIdx.x, wid = t >> 6, lane = t & 63;
    int k = blockIdx.x * 4 + wid;
    if (k >= K) return;
    int p0 = offs[k], p1 = offs[k + 1];
    if (p0 >= p1) return;
    u16* tb = tbAll[wid];
    u16* wt = WT[wid];

    int l15 = lane & 15, l4 = lane >> 4;
    const float* Wg = W + (size_t)k * (IN * OUT);
    for (int f = lane; f < IN * OUT; f += 64) {
        int r = f / OUT, c = f - r * OUT;
        wt[c * 72 + r] = f2bf(Wg[f]);
    }
    bf16x8 breg[2];
    #pragma unroll
    for (int ks = 0; ks < 2; ks++)
        breg[ks] = (l15 < OUT) ? *(const bf16x8*)&wt[l15 * 72 + ks * 32 + l4 * 8]
                               : bf16x8{0, 0, 0, 0, 0, 0, 0, 0};

    for (int t0 = p0; t0 < p1; t0 += 16) {
        int np = min(16, p1 - t0);
        int4 meta = pairP[min(t0 + l15, p1 - 1)];
        float basv = (l15 < np) ? __int_as_float(meta.y) : 0.0f;
        int srv = meta.z;
        const u16* xrow = xbf + (size_t)meta.x * IN + l4 * 8;
        f32x4 acc = f32x4{0.f, 0.f, 0.f, 0.f};
        #pragma unroll
        for (int ks = 0; ks < 2; ks++) {
            bf16x8 a = *(const bf16x8*)(xrow + ks * 32);
            acc = __builtin_amdgcn_mfma_f32_16x16x32_bf16(a, breg[ks], acc, 0, 0, 0);
        }
        #pragma unroll
        for (int r = 0; r < 4; r++) {
            int pl = l4 * 4 + r;
            float bs = __shfl(basv, pl);
            tb[pl * 24 + l15] = f2bf(acc[r] * bs);
        }
        {
            int row = lane >> 1, ch = lane & 1;
            int srr = __shfl(srv, row);
            if (lane < np * 2)
                __builtin_nontemporal_store(
                    *(const bf16x8*)&tb[row * 24 + ch * 8],
                    (bf16x8*)(mpart + (size_t)srr * OUT16 + ch * 8));
        }
    }
}

// ---------------- streaming segment reduce (32B NT loads) + mean + root + bias ----------------
template <int IN, int OUT, int OUT16, bool HEAD>
__global__ __launch_bounds__(256) void reduce_mfma(
    const u16* __restrict__ mpart, const int* __restrict__ eoff,
    const float* __restrict__ xin, const float* __restrict__ Wr,
    const float* __restrict__ bias, float* __restrict__ hout,
    u16* __restrict__ hbf, int N) {
    int n = blockIdx.x;
    int e0 = eoff[n], e1 = eoff[n + 1];
    int R = (e1 - e0) * SCOR;
    size_t rs = (size_t)e0 * SCOR;
    constexpr int CH = OUT16 / 16;   // 32B chunks per row
    constexpr int G = 256 / CH;
    int t = threadIdx.x;
    int ch = t % CH, rg = t / CH;
    float a[16];
    #pragma unroll
    for (int j = 0; j < 16; j++) a[j] = 0.0f;
    #pragma unroll 2
    for (int r = rg; r < R; r += G) {
        const u16* mp = mpart + (rs + r) * OUT16 + ch * 16;
        bf16x8 v0 = __builtin_nontemporal_load((const bf16x8*)mp);
        bf16x8 v1 = __builtin_nontemporal_load((const bf16x8*)(mp + 8));
        #pragma unroll
        for (int j = 0; j < 8; j++) a[j] += bf2f(((const u16*)&v0)[j]);
        #pragma unroll
        for (int j = 0; j < 8; j++) a[8 + j] += bf2f(((const u16*)&v1)[j]);
    }
    __shared__ float part[256 * 17];
    #pragma unroll
    for (int j = 0; j < 16; j++) part[t * 17 + j] = a[j];
    __syncthreads();
    for (int h = G / 2; h >= 1; h >>= 1) {
        if (rg < h) {
            #pragma unroll
            for (int j = 0; j < 16; j++)
                part[t * 17 + j] += part[(t + h * CH) * 17 + j];
        }
        __syncthreads();
    }
    __shared__ float sm[16];
    if (t < OUT) {
        float s = part[(t / 16) * 17 + (t % 16)];
        int dg = e1 - e0;
        s /= (dg < 1) ? 1.0f : (float)dg;
        s += bias[t];
        const float* xr = xin + (size_t)n * IN;
        #pragma unroll 8
        for (int i = 0; i < IN; i++) s += xr[i] * Wr[i * OUT + t];
        if constexpr (HEAD) {
            sm[t] = s;
        } else {
            hout[(size_t)n * OUT + t] = s;
            if (hbf) hbf[(size_t)n * OUT + t] = f2bf(s);
        }
    }
    if constexpr (HEAD) {
        __syncthreads();
        if (t < OUT) {
            float v[13];
            float mx = -1e30f;
            #pragma unroll
            for (int c = 0; c < 13; c++) {
                float z = sm[c];
                z = z > 0.0f ? z : (expf(z) - 1.0f);
                v[c] = z;
                mx = fmaxf(mx, z);
            }
            float sum = 0.0f;
            #pragma unroll
            for (int c = 0; c < 13; c++) sum += expf(v[c] - mx);
            float lse = mx + logf(sum);
            hout[(size_t)n * 13 + t] = v[t] - lse;
        }
    }
}

extern "C" void kernel_launch(void* const* d_in, const int* in_sizes, int n_in,
                              void* d_out, int out_size, void* d_ws, size_t ws_size,
                              hipStream_t stream) {
    const float* x   = (const float*)d_in[0];
    const int*   ei  = (const int*)d_in[1];
    const float* ea  = (const float*)d_in[2];
    const float* W1  = (const float*)d_in[3];
    const float* Wr1 = (const float*)d_in[4];
    const float* b1  = (const float*)d_in[5];
    const float* W3  = (const float*)d_in[6];
    const float* Wr3 = (const float*)d_in[7];
    const float* b3  = (const float*)d_in[8];
    const float* W6  = (const float*)d_in[9];
    const float* Wr6 = (const float*)d_in[10];
    const float* b6  = (const float*)d_in[11];
    const float* W7  = (const float*)d_in[12];
    const float* Wr7 = (const float*)d_in[13];
    const float* b7  = (const float*)d_in[14];

    const int N = in_sizes[0] / 32;
    const int E = in_sizes[1] / 2;
    const int* src = ei;
    const int* dst = ei + E;
    (void)n_in; (void)out_size; (void)ws_size;

    const int K3 = 729, K5 = 15625, K7 = 117649;
    const int P = E * SCOR;

    const int BS = 1024;
    const int Np = (N + BS - 1) / BS * BS;
    const int nb0 = Np / BS;
    const int P3 = 1024, P5 = 16384, P7 = 117760;
    const int totalPad = Np + P3 + P5 + P7;
    const int nBlocks = nb0 + 1 + 16 + 115;

    char* ws = (char*)d_ws;
    size_t off = 0;
    auto alloc = [&](size_t bytes) {
        void* p = ws + off;
        off += (bytes + 255) & ~(size_t)255;
        return p;
    };
    int*   zb    = (int*)alloc((size_t)totalPad * 4);
    int*   degi  = zb;
    int*   cnt3  = zb + Np;
    int*   cnt5  = cnt3 + P3;
    int*   cnt7  = cnt5 + P5;
    int*   bsum  = (int*)alloc((size_t)nBlocks * 4);
    int*   eoff  = (int*)alloc((size_t)(N + 1) * 4);
    int*   offs3 = (int*)alloc((size_t)(K3 + 1) * 4);
    int*   offs5 = (int*)alloc((size_t)(K5 + 1) * 4);
    int*   offs7 = (int*)alloc((size_t)(K7 + 1) * 4);
    int4*  pP3   = (int4*)alloc((size_t)P * 16);
    int4*  pP5   = (int4*)alloc((size_t)P * 16);
    int4*  pP7   = (int4*)alloc((size_t)P * 16);
    float* h1    = (float*)alloc((size_t)N * 128 * 4);
    float* h3    = (float*)alloc((size_t)N * 128 * 4);
    float* h6    = (float*)alloc((size_t)N * 64 * 4);
    u16*   xbf1  = (u16*)alloc((size_t)N * 32 * 2);
    u16*   hbf1  = (u16*)alloc((size_t)N * 128 * 2);
    u16*   hbf3  = (u16*)alloc((size_t)N * 128 * 2);
    u16*   hbf6  = (u16*)alloc((size_t)N * 64 * 2);
    u16*   mpart = (u16*)alloc((size_t)P * 128 * 2);  // 256 MiB

    dim3 blk(256);
    dim3 pgrid((P + 255) / 256);

    // zero counters + x -> bf16 (fused)
    int n4 = N * 32 / 4;
    prep_kernel<<<(max(totalPad, n4) + 255) / 256, blk, 0, stream>>>(zb, totalPad, x, xbf1, n4);

    // fused counting (3 ks + degree)
    count_all<<<pgrid, blk, 0, stream>>>(ea, dst, cnt3, cnt5, cnt7, degi, P);

    // parallel segmented scan
    scan_partial<<<nBlocks, blk, 0, stream>>>(zb, bsum);
    scan_final<<<nBlocks, blk, 0, stream>>>(zb, bsum, eoff, offs3, offs5, offs7, N, nb0);

    // fused fill (3 ks + per-edge dst-rank, node stored in metadata)
    fill_all<<<pgrid, blk, 0, stream>>>(ea, src, dst, degi, cnt3, pP3, cnt5, pP5, cnt7, pP7, P);

    // layer 1: 32 -> 128
    conv_mfma_r<32, 128, 8, 2, 4><<<dim3(K3, 4), dim3(512), 0, stream>>>(
        xbf1, W1, offs3, pP3, mpart);
    reduce_mfma<32, 128, 128, false><<<N, blk, 0, stream>>>(mpart, eoff, x, Wr1, b1, h1, hbf1, N);

    // layer 3: 128 -> 128 (GY=4: better one-time-cost amortization per wave)
    conv_mfma_r<128, 128, 8, 2, 4><<<dim3(K3, 4), dim3(512), 0, stream>>>(
        hbf1, W3, offs3, pP3, mpart);
    reduce_mfma<128, 128, 128, false><<<N, blk, 0, stream>>>(mpart, eoff, h1, Wr3, b3, h3, hbf3, N);

    // layer 6: 128 -> 64
    conv_mfma_r<128, 64, 4, 2, 1><<<dim3(K5, 1), blk, 0, stream>>>(
        hbf3, W6, offs5, pP5, mpart);
    reduce_mfma<128, 64, 64, false><<<N, blk, 0, stream>>>(mpart, eoff, h3, Wr6, b6, h6, hbf6, N);

    // layer 7: 64 -> 13 (wave per bucket) + fused ELU/log_softmax head
    conv_mfma_w7<<<(K7 + 3) / 4, blk, 0, stream>>>(hbf6, W7, offs7, pP7, mpart, K7);
    reduce_mfma<64, 13, 16, true><<<N, blk, 0, stream>>>(mpart, eoff, h6, Wr7, b7, (float*)d_out, nullptr, N);
}

// Round 12
// 1247.088 us; speedup vs baseline: 1.2138x; 1.0119x over previous
//
#include <hip/hip_runtime.h>
#include <hip/hip_bf16.h>
#include <cstdint>
#include <cstddef>

constexpr int SDIM = 6;
constexpr int SCOR = 64;   // 2^6 corners
typedef unsigned short u16;
typedef __attribute__((ext_vector_type(8))) short bf16x8;
typedef __attribute__((ext_vector_type(4))) float f32x4;

__device__ __forceinline__ float bf2f(u16 h) {
    union { unsigned u; float f; } v; v.u = ((unsigned)h) << 16; return v.f;
}
__device__ __forceinline__ u16 f2bf(float f) {
    union { float f; unsigned u; } v; v.f = f;
    unsigned r = v.u + 0x7fffu + ((v.u >> 16) & 1u);
    return (u16)(r >> 16);
}

template <int KS>
__device__ __forceinline__ void keybasis(const float* u, int s, int& key, float& basis) {
    int idx = 0, str = 1;
    float b = 1.0f;
    #pragma unroll
    for (int d = 0; d < SDIM; d++) {
        float v = u[d] * (KS - 1);
        float fl = floorf(v);
        float fr = v - fl;
        int bit = (s >> d) & 1;
        int pos = (int)fl + bit;
        pos = min(max(pos, 0), KS - 1);
        idx += pos * str;
        str *= KS;
        b *= bit ? fr : (1.0f - fr);
    }
    key = idx;
    basis = b;
}

// ---------------- fused zero + fp32->bf16 ----------------
__global__ __launch_bounds__(256) void prep_kernel(int* __restrict__ zb, int nz,
                                                   const float* __restrict__ xin,
                                                   u16* __restrict__ xbf, int n4) {
    int i = blockIdx.x * blockDim.x + threadIdx.x;
    if (i < nz) zb[i] = 0;
    if (i < n4) {
        float4 v = ((const float4*)xin)[i];
        ushort4 o;
        o.x = f2bf(v.x); o.y = f2bf(v.y); o.z = f2bf(v.z); o.w = f2bf(v.w);
        ((ushort4*)xbf)[i] = o;
    }
}

// ---------------- fused counting: 3 ks + degree; cnt3 replicated x8 ----------------
__global__ __launch_bounds__(256) void count_all(const float* __restrict__ ea,
                                                 const int* __restrict__ dst,
                                                 int* __restrict__ cnt3r,
                                                 int* __restrict__ cnt5,
                                                 int* __restrict__ cnt7,
                                                 int* __restrict__ degi, int P) {
    int gid = blockIdx.x * blockDim.x + threadIdx.x;
    if (gid >= P) return;
    int e = gid >> 6, s = gid & 63;
    int rep = blockIdx.x & 7;
    float u[SDIM];
    #pragma unroll
    for (int d = 0; d < SDIM; d++) u[d] = ea[e * SDIM + d];
    int k; float b;
    keybasis<3>(u, s, k, b); atomicAdd(&cnt3r[k * 8 + rep], 1);
    keybasis<5>(u, s, k, b); atomicAdd(&cnt5[k], 1);
    keybasis<7>(u, s, k, b); atomicAdd(&cnt7[k], 1);
    if (s == 0) atomicAdd(&degi[dst[e]], 1);
}

// ---------------- parallel segmented scan over zb = [deg|cnt3r|cnt5|cnt7] ----------------
__global__ __launch_bounds__(256) void scan_partial(const int* __restrict__ zb,
                                                    int* __restrict__ bsum) {
    int b = blockIdx.x, t = threadIdx.x;
    int4 v = *(const int4*)(zb + b * 1024 + t * 4);
    __shared__ int red[256];
    red[t] = v.x + v.y + v.z + v.w;
    __syncthreads();
    for (int h = 128; h >= 1; h >>= 1) {
        if (t < h) red[t] += red[t + h];
        __syncthreads();
    }
    if (t == 0) bsum[b] = red[0];
}

__global__ __launch_bounds__(256) void scan_final(int* __restrict__ zb,
                                                  const int* __restrict__ bsum,
                                                  int* __restrict__ eoff,
                                                  int* __restrict__ offs3f,
                                                  int* __restrict__ offs5,
                                                  int* __restrict__ offs7,
                                                  int Nn, int nb0) {
    int b = blockIdx.x, t = threadIdx.x;
    int s1 = nb0, s2 = nb0 + 6, s3 = nb0 + 22;   // cnt3r pad 6144, cnt5 pad 16384
    int seg = (b >= s3) ? 3 : (b >= s2) ? 2 : (b >= s1) ? 1 : 0;
    int sb = (seg == 0) ? 0 : (seg == 1) ? s1 : (seg == 2) ? s2 : s3;
    int L = (seg == 0) ? Nn : (seg == 1) ? 5832 : (seg == 2) ? 15625 : 117649;
    int* offs = (seg == 0) ? eoff : (seg == 1) ? offs3f : (seg == 2) ? offs5 : offs7;

    __shared__ int red[256];
    int cnt = b - sb;
    int acc = 0;
    for (int j = t; j < cnt; j += 256) acc += bsum[sb + j];
    red[t] = acc;
    __syncthreads();
    for (int h = 128; h >= 1; h >>= 1) {
        if (t < h) red[t] += red[t + h];
        __syncthreads();
    }
    int blockPrefix = red[0];
    __syncthreads();

    int idx = b * 1024 + t * 4;
    int4 v = *(const int4*)(zb + idx);
    int tsum = v.x + v.y + v.z + v.w;
    __shared__ int ss[256];
    ss[t] = tsum;
    __syncthreads();
    for (int off = 1; off < 256; off <<= 1) {
        int val = (t >= off) ? ss[t - off] : 0;
        __syncthreads();
        ss[t] += val;
        __syncthreads();
    }
    int p = blockPrefix + ((t == 0) ? 0 : ss[t - 1]);
    int pe[4];
    pe[0] = p;
    pe[1] = p + v.x;
    pe[2] = pe[1] + v.y;
    pe[3] = pe[2] + v.z;
    int vv[4] = {v.x, v.y, v.z, v.w};
    int li = (b - sb) * 1024 + t * 4;
    #pragma unroll
    for (int j = 0; j < 4; j++) {
        int gi = li + j;
        if (gi < L) {
            offs[gi] = pe[j];
            zb[idx + j] = pe[j];   // cursor init
            if (gi == L - 1) offs[L] = pe[j] + vv[j];
        }
    }
}

// ---------------- fused fill: one wave = one edge; lane = corner ----------------
// meta = {node<<20 | er64, basis} (8B). cur3r replicated x8 by blockIdx.
__global__ __launch_bounds__(256) void fill_all(const float* __restrict__ ea,
                                                const int* __restrict__ src,
                                                const int* __restrict__ dst,
                                                int* __restrict__ ecur,
                                                int* __restrict__ cur3r, int2* __restrict__ pP3,
                                                int* __restrict__ cur5, int2* __restrict__ pP5,
                                                int* __restrict__ cur7, int2* __restrict__ pP7,
                                                int P) {
    int gid = blockIdx.x * blockDim.x + threadIdx.x;
    if (gid >= P) return;
    int e = gid >> 6;
    int lane = threadIdx.x & 63;   // == corner s
    int rep = blockIdx.x & 7;
    float u[SDIM];
    #pragma unroll
    for (int d = 0; d < SDIM; d++) u[d] = ea[e * SDIM + d];
    int node = src[e];
    int er = 0;
    if (lane == 0) er = atomicAdd(&ecur[dst[e]], 1);
    er = __shfl(er, 0);
    int packed = (node << 20) | (er * SCOR + lane);
    int k; float b; int slot;
    keybasis<3>(u, lane, k, b);
    slot = atomicAdd(&cur3r[k * 8 + rep], 1);
    pP3[slot] = make_int2(packed, __float_as_int(b));
    keybasis<5>(u, lane, k, b);
    slot = atomicAdd(&cur5[k], 1);
    pP5[slot] = make_int2(packed, __float_as_int(b));
    keybasis<7>(u, lane, k, b);
    slot = atomicAdd(&cur7[k], 1);
    pP7[slot] = make_int2(packed, __float_as_int(b));
}

// ---------------- MFMA bucketed conv ----------------
// OSTR: stride in the offsets array (8 for the replicated ks=3 layout).
template <int IN, int OUT, int WAVES, int WN, int GY, int OSTR>
__global__ __launch_bounds__(WAVES * 64) void conv_mfma_r(
    const u16* __restrict__ xbf, const float* __restrict__ W,
    const int* __restrict__ offs, const int2* __restrict__ pairP,
    u16* __restrict__ mpart) {
    constexpr int NT = WAVES * 64;
    constexpr int WM = WAVES / WN;
    constexpr int OUT16 = (OUT + 15) & ~15;
    static_assert(OUT == OUT16, "conv_mfma_r requires OUT multiple of 16");
    constexpr int WSTR = OUT + 2;    // padded LDS row stride
    constexpr int NF = OUT16 / 16;
    constexpr int NFW = NF / WN;
    constexpr int KS = IN / 32;
    constexpr int TW = NFW * 16;
    constexpr int TSTR = TW + 8;
    constexpr int CHW = TW / 8;
    static_assert((TSTR * 2) % 16 == 0, "row stride must be 16B aligned");
    static_assert((IN * OUT) % NT == 0, "staging divisibility");

    __shared__ u16 Wlds[IN * WSTR];
    __shared__ u16 tall[WAVES][16 * TSTR];

    int k = blockIdx.x;
    int p0 = offs[k * OSTR], p1 = offs[(k + 1) * OSTR];
    int t = threadIdx.x;
    int wid = t >> 6, lane = t & 63;
    int wm = wid % WM, wn = wid / WM;
    int l15 = lane & 15, l4 = lane >> 4;
    u16* twave = tall[wid];

    if (p0 + (int)blockIdx.y * WM * 16 >= p1) return;

    // stage W[k]: coalesced fp32 -> bf16, padded row-major LDS
    const float* Wg = W + (size_t)k * IN * OUT;
    #pragma unroll
    for (int f0 = 0; f0 < IN * OUT; f0 += NT) {
        int f = f0 + t;
        int i = f / OUT, o = f % OUT;
        Wlds[i * WSTR + o] = f2bf(Wg[f]);
    }
    __syncthreads();

    // one-time assembly of B fragments (stride 65 dw -> bank-spread)
    bf16x8 breg[KS][NFW];
    #pragma unroll
    for (int ks = 0; ks < KS; ks++) {
        #pragma unroll
        for (int nf = 0; nf < NFW; nf++) {
            int col = (wn * NFW + nf) * 16 + l15;
            int rbase = ks * 32 + l4 * 8;
            bf16x8 b;
            #pragma unroll
            for (int j = 0; j < 8; j++)
                ((u16*)&b)[j] = Wlds[(rbase + j) * WSTR + col];
            breg[ks][nf] = b;
        }
    }

    constexpr int STRIDE = WM * GY * 16;
    int t0 = p0 + ((int)blockIdx.y * WM + wm) * 16;
    if (t0 >= p1) return;

    int2 meta = pairP[min(t0 + l15, p1 - 1)];
    bf16x8 a[KS];
    {
        const u16* xrow = xbf + (size_t)((unsigned)meta.x >> 20) * IN + l4 * 8;
        #pragma unroll
        for (int ks = 0; ks < KS; ks++) a[ks] = *(const bf16x8*)(xrow + ks * 32);
    }

    while (true) {
        int np = min(16, p1 - t0);
        float basv = (l15 < np) ? __int_as_float(meta.y) : 0.0f;
        int srv = meta.x & 0xFFFFF;
        int tn = t0 + STRIDE;
        bool has = tn < p1;
        int2 metaN = meta;
        if (has) metaN = pairP[min(tn + l15, p1 - 1)];   // issue early

        f32x4 acc[NFW];
        #pragma unroll
        for (int nf = 0; nf < NFW; nf++)
            acc[nf] = f32x4{0.f, 0.f, 0.f, 0.f};
        #pragma unroll
        for (int ks = 0; ks < KS; ks++) {
            #pragma unroll
            for (int nf = 0; nf < NFW; nf++)
                acc[nf] = __builtin_amdgcn_mfma_f32_16x16x32_bf16(a[ks], breg[ks][nf], acc[nf], 0, 0, 0);
        }

        bf16x8 aN[KS];
        if (has) {
            const u16* xrowN = xbf + (size_t)((unsigned)metaN.x >> 20) * IN + l4 * 8;
            #pragma unroll
            for (int ks = 0; ks < KS; ks++) aN[ks] = *(const bf16x8*)(xrowN + ks * 32);
        }

        #pragma unroll
        for (int nf = 0; nf < NFW; nf++) {
            #pragma unroll
            for (int r = 0; r < 4; r++) {
                int pl = l4 * 4 + r;
                float bs = __shfl(basv, pl);
                twave[pl * TSTR + nf * 16 + l15] = f2bf(acc[nf][r] * bs);
            }
        }

        #pragma unroll
        for (int it = 0; it < (16 * CHW + 63) / 64; it++) {
            int cid = it * 64 + lane;
            int row = cid / CHW, ch = cid % CHW;
            int srr = __shfl(srv, row);
            if (row < np)
                __builtin_nontemporal_store(
                    *(const bf16x8*)&twave[row * TSTR + ch * 8],
                    (bf16x8*)(mpart + (size_t)srr * OUT16 + wn * TW + ch * 8));
        }

        if (!has) break;
        t0 = tn;
        meta = metaN;
        #pragma unroll
        for (int ks = 0; ks < KS; ks++) a[ks] = aN[ks];
    }
}

// ---------------- wave-per-bucket conv for ks=7 (IN=64, OUT=13) ----------------
__global__ __launch_bounds__(256) void conv_mfma_w7(
    const u16* __restrict__ xbf, const float* __restrict__ W,
    const int* __restrict__ offs, const int2* __restrict__ pairP,
    u16* __restrict__ mpart, int K) {
    constexpr int IN = 64, OUT = 13, OUT16 = 16;
    __shared__ u16 WT[4][16 * 72];
    __shared__ u16 tbAll[4][16 * 24];
    int t = threadIdx.x, wid = t >> 6, lane = t & 63;
    int k = blockIdx.x * 4 + wid;
    if (k >= K) return;
    int p0 = offs[k], p1 = offs[k + 1];
    if (p0 >= p1) return;
    u16* tb = tbAll[wid];
    u16* wt = WT[wid];

    int l15 = lane & 15, l4 = lane >> 4;
    const float* Wg = W + (size_t)k * (IN * OUT);
    for (int f = lane; f < IN * OUT; f += 64) {
        int r = f / OUT, c = f - r * OUT;
        wt[c * 72 + r] = f2bf(Wg[f]);
    }
    bf16x8 breg[2];
    #pragma unroll
    for (int ks = 0; ks < 2; ks++)
        breg[ks] = (l15 < OUT) ? *(const bf16x8*)&wt[l15 * 72 + ks * 32 + l4 * 8]
                               : bf16x8{0, 0, 0, 0, 0, 0, 0, 0};

    for (int t0 = p0; t0 < p1; t0 += 16) {
        int np = min(16, p1 - t0);
        int2 meta = pairP[min(t0 + l15, p1 - 1)];
        float basv = (l15 < np) ? __int_as_float(meta.y) : 0.0f;
        int srv = meta.x & 0xFFFFF;
        const u16* xrow = xbf + (size_t)((unsigned)meta.x >> 20) * IN + l4 * 8;
        f32x4 acc = f32x4{0.f, 0.f, 0.f, 0.f};
        #pragma unroll
        for (int ks = 0; ks < 2; ks++) {
            bf16x8 a = *(const bf16x8*)(xrow + ks * 32);
            acc = __builtin_amdgcn_mfma_f32_16x16x32_bf16(a, breg[ks], acc, 0, 0, 0);
        }
        #pragma unroll
        for (int r = 0; r < 4; r++) {
            int pl = l4 * 4 + r;
            float bs = __shfl(basv, pl);
            tb[pl * 24 + l15] = f2bf(acc[r] * bs);
        }
        {
            int row = lane >> 1, ch = lane & 1;
            int srr = __shfl(srv, row);
            if (lane < np * 2)
                __builtin_nontemporal_store(
                    *(const bf16x8*)&tb[row * 24 + ch * 8],
                    (bf16x8*)(mpart + (size_t)srr * OUT16 + ch * 8));
        }
    }
}

// ---------------- streaming segment reduce (32B NT loads) + mean + root + bias ----------------
template <int IN, int OUT, int OUT16, bool HEAD>
__global__ __launch_bounds__(256) void reduce_mfma(
    const u16* __restrict__ mpart, const int* __restrict__ eoff,
    const float* __restrict__ xin, const float* __restrict__ Wr,
    const float* __restrict__ bias, float* __restrict__ hout,
    u16* __restrict__ hbf, int N) {
    int n = blockIdx.x;
    int e0 = eoff[n], e1 = eoff[n + 1];
    int R = (e1 - e0) * SCOR;
    size_t rs = (size_t)e0 * SCOR;
    constexpr int CH = OUT16 / 16;
    constexpr int G = 256 / CH;
    int t = threadIdx.x;
    int ch = t % CH, rg = t / CH;
    float a[16];
    #pragma unroll
    for (int j = 0; j < 16; j++) a[j] = 0.0f;
    #pragma unroll 2
    for (int r = rg; r < R; r += G) {
        const u16* mp = mpart + (rs + r) * OUT16 + ch * 16;
        bf16x8 v0 = __builtin_nontemporal_load((const bf16x8*)mp);
        bf16x8 v1 = __builtin_nontemporal_load((const bf16x8*)(mp + 8));
        #pragma unroll
        for (int j = 0; j < 8; j++) a[j] += bf2f(((const u16*)&v0)[j]);
        #pragma unroll
        for (int j = 0; j < 8; j++) a[8 + j] += bf2f(((const u16*)&v1)[j]);
    }
    __shared__ float part[256 * 17];
    #pragma unroll
    for (int j = 0; j < 16; j++) part[t * 17 + j] = a[j];
    __syncthreads();
    for (int h = G / 2; h >= 1; h >>= 1) {
        if (rg < h) {
            #pragma unroll
            for (int j = 0; j < 16; j++)
                part[t * 17 + j] += part[(t + h * CH) * 17 + j];
        }
        __syncthreads();
    }
    __shared__ float sm[16];
    if (t < OUT) {
        float s = part[(t / 16) * 17 + (t % 16)];
        int dg = e1 - e0;
        s /= (dg < 1) ? 1.0f : (float)dg;
        s += bias[t];
        const float* xr = xin + (size_t)n * IN;
        #pragma unroll 8
        for (int i = 0; i < IN; i++) s += xr[i] * Wr[i * OUT + t];
        if constexpr (HEAD) {
            sm[t] = s;
        } else {
            hout[(size_t)n * OUT + t] = s;
            if (hbf) hbf[(size_t)n * OUT + t] = f2bf(s);
        }
    }
    if constexpr (HEAD) {
        __syncthreads();
        if (t < OUT) {
            float v[13];
            float mx = -1e30f;
            #pragma unroll
            for (int c = 0; c < 13; c++) {
                float z = sm[c];
                z = z > 0.0f ? z : (expf(z) - 1.0f);
                v[c] = z;
                mx = fmaxf(mx, z);
            }
            float sum = 0.0f;
            #pragma unroll
            for (int c = 0; c < 13; c++) sum += expf(v[c] - mx);
            float lse = mx + logf(sum);
            hout[(size_t)n * 13 + t] = v[t] - lse;
        }
    }
}

extern "C" void kernel_launch(void* const* d_in, const int* in_sizes, int n_in,
                              void* d_out, int out_size, void* d_ws, size_t ws_size,
                              hipStream_t stream) {
    const float* x   = (const float*)d_in[0];
    const int*   ei  = (const int*)d_in[1];
    const float* ea  = (const float*)d_in[2];
    const float* W1  = (const float*)d_in[3];
    const float* Wr1 = (const float*)d_in[4];
    const float* b1  = (const float*)d_in[5];
    const float* W3  = (const float*)d_in[6];
    const float* Wr3 = (const float*)d_in[7];
    const float* b3  = (const float*)d_in[8];
    const float* W6  = (const float*)d_in[9];
    const float* Wr6 = (const float*)d_in[10];
    const float* b6  = (const float*)d_in[11];
    const float* W7  = (const float*)d_in[12];
    const float* Wr7 = (const float*)d_in[13];
    const float* b7  = (const float*)d_in[14];

    const int N = in_sizes[0] / 32;
    const int E = in_sizes[1] / 2;
    const int* src = ei;
    const int* dst = ei + E;
    (void)n_in; (void)out_size; (void)ws_size;

    const int K3 = 729, K5 = 15625, K7 = 117649;
    const int P = E * SCOR;

    const int BS = 1024;
    const int Np = (N + BS - 1) / BS * BS;
    const int nb0 = Np / BS;
    const int P3 = 6144, P5 = 16384, P7 = 117760;   // cnt3 replicated x8 (5832) pad 6144
    const int totalPad = Np + P3 + P5 + P7;
    const int nBlocks = nb0 + 6 + 16 + 115;

    char* ws = (char*)d_ws;
    size_t off = 0;
    auto alloc = [&](size_t bytes) {
        void* p = ws + off;
        off += (bytes + 255) & ~(size_t)255;
        return p;
    };
    int*   zb    = (int*)alloc((size_t)totalPad * 4);
    int*   degi  = zb;
    int*   cnt3r = zb + Np;
    int*   cnt5  = cnt3r + P3;
    int*   cnt7  = cnt5 + P5;
    int*   bsum  = (int*)alloc((size_t)nBlocks * 4);
    int*   eoff  = (int*)alloc((size_t)(N + 1) * 4);
    int*   offs3f = (int*)alloc((size_t)(K3 * 8 + 1) * 4);
    int*   offs5 = (int*)alloc((size_t)(K5 + 1) * 4);
    int*   offs7 = (int*)alloc((size_t)(K7 + 1) * 4);
    int2*  pP3   = (int2*)alloc((size_t)P * 8);
    int2*  pP5   = (int2*)alloc((size_t)P * 8);
    int2*  pP7   = (int2*)alloc((size_t)P * 8);
    float* h1    = (float*)alloc((size_t)N * 128 * 4);
    float* h3    = (float*)alloc((size_t)N * 128 * 4);
    float* h6    = (float*)alloc((size_t)N * 64 * 4);
    u16*   xbf1  = (u16*)alloc((size_t)N * 32 * 2);
    u16*   hbf1  = (u16*)alloc((size_t)N * 128 * 2);
    u16*   hbf3  = (u16*)alloc((size_t)N * 128 * 2);
    u16*   hbf6  = (u16*)alloc((size_t)N * 64 * 2);
    u16*   mpart = (u16*)alloc((size_t)P * 128 * 2);  // 256 MiB

    dim3 blk(256);
    dim3 pgrid((P + 255) / 256);

    // zero counters + x -> bf16 (fused)
    int n4 = N * 32 / 4;
    prep_kernel<<<(max(totalPad, n4) + 255) / 256, blk, 0, stream>>>(zb, totalPad, x, xbf1, n4);

    // fused counting (3 ks + degree; cnt3 replicated x8)
    count_all<<<pgrid, blk, 0, stream>>>(ea, dst, cnt3r, cnt5, cnt7, degi, P);

    // parallel segmented scan
    scan_partial<<<nBlocks, blk, 0, stream>>>(zb, bsum);
    scan_final<<<nBlocks, blk, 0, stream>>>(zb, bsum, eoff, offs3f, offs5, offs7, N, nb0);

    // fused fill (3 ks + per-edge dst-rank; packed 8B metadata)
    fill_all<<<pgrid, blk, 0, stream>>>(ea, src, dst, degi, cnt3r, pP3, cnt5, pP5, cnt7, pP7, P);

    // layer 1: 32 -> 128 (GY=8: halve hot-bucket tail)
    conv_mfma_r<32, 128, 8, 2, 8, 8><<<dim3(K3, 8), dim3(512), 0, stream>>>(
        xbf1, W1, offs3f, pP3, mpart);
    reduce_mfma<32, 128, 128, false><<<N, blk, 0, stream>>>(mpart, eoff, x, Wr1, b1, h1, hbf1, N);

    // layer 3: 128 -> 128 (GY=8)
    conv_mfma_r<128, 128, 8, 2, 8, 8><<<dim3(K3, 8), dim3(512), 0, stream>>>(
        hbf1, W3, offs3f, pP3, mpart);
    reduce_mfma<128, 128, 128, false><<<N, blk, 0, stream>>>(mpart, eoff, h1, Wr3, b3, h3, hbf3, N);

    // layer 6: 128 -> 64
    conv_mfma_r<128, 64, 4, 2, 1, 1><<<dim3(K5, 1), blk, 0, stream>>>(
        hbf3, W6, offs5, pP5, mpart);
    reduce_mfma<128, 64, 64, false><<<N, blk, 0, stream>>>(mpart, eoff, h3, Wr6, b6, h6, hbf6, N);

    // layer 7: 64 -> 13 (wave per bucket) + fused ELU/log_softmax head
    conv_mfma_w7<<<(K7 + 3) / 4, blk, 0, stream>>>(hbf6, W7, offs7, pP7, mpart, K7);
    reduce_mfma<64, 13, 16, true><<<N, blk, 0, stream>>>(mpart, eoff, h6, Wr7, b7, (float*)d_out, nullptr, N);
}